// Round 3
// baseline (140.869 us; speedup 1.0000x reference)
//
#include <hip/hip_runtime.h>
#include <hip/hip_cooperative_groups.h>
#include <math.h>

#define BLOCK 256
#define KB_ 16384   // number of value buckets

namespace cg = cooperative_groups;

// Single fused cooperative kernel:
//  P0 zero hist; P1 exp+bucket+atomic hist (rank via atomic); P2 block0 scans
//  (prefix counts -> offsets, suffix bucketE -> suffixE); P3 counting-sort
//  scatter; P4 risk = suffixE[b+1] + exact in-bucket scan, term, reduce;
//  P5 write -mean.
__global__ void surv_fused(const float* __restrict__ theta,
                           const float* __restrict__ T,
                           const float* __restrict__ events,
                           float* __restrict__ out,
                           int* __restrict__ counts,    // [KB_]
                           int* __restrict__ offsets,   // [KB_+1]
                           float* __restrict__ bucketE, // [KB_]
                           float* __restrict__ suffixE, // [KB_+1]
                           float* __restrict__ sortedT, // [n]
                           float* __restrict__ sortedE, // [n]
                           float* __restrict__ acc,     // [1]
                           int n) {
    cg::grid_group grid = cg::this_grid();
    const int g = blockIdx.x * BLOCK + threadIdx.x;
    const int nthreads = gridDim.x * BLOCK;

    // ---- P0: zero histogram state ----
    for (int b = g; b < KB_; b += nthreads) { counts[b] = 0; bucketE[b] = 0.f; }
    if (g == 0) { acc[0] = 0.f; offsets[KB_] = n; suffixE[KB_] = 0.f; }
    grid.sync();

    // ---- P1: exp + bucket + histogram (rank from atomic) ----
    float Tg = 0.f, Eg = 0.f, thg = 0.f, evg = 0.f;
    int bg = 0, rg = 0;
    if (g < n) {
        Tg = T[g]; thg = theta[g]; evg = events[g];
        Eg = expf(thg);
        int b = (int)((Tg + 6.0f) * (KB_ / 12.0f));
        if (b < 0) b = 0;
        if (b > KB_ - 1) b = KB_ - 1;
        bg = b;
        rg = atomicAdd(&counts[bg], 1);
        atomicAdd(&bucketE[bg], Eg);
    }
    grid.sync();

    // ---- P2: block 0 scans (others wait at next sync) ----
    if (blockIdx.x == 0) {
        __shared__ int   csum[BLOCK];
        __shared__ float esum[BLOCK];
        const int t = threadIdx.x;
        const int chunk = KB_ / BLOCK;           // 64
        const int base = t * chunk;
        int cs = 0; float es = 0.f;
        for (int k = 0; k < chunk; ++k) { cs += counts[base + k]; es += bucketE[base + k]; }
        csum[t] = cs; esum[t] = es;
        __syncthreads();
        if (t == 0) {
            int run = 0;
            for (int u = 0; u < BLOCK; ++u) { int c = csum[u]; csum[u] = run; run += c; }
            float rs = 0.f;
            for (int u = BLOCK - 1; u >= 0; --u) { float e = esum[u]; esum[u] = rs; rs += e; }
        }
        __syncthreads();
        int run = csum[t];                        // exclusive prefix of counts
        for (int k = 0; k < chunk; ++k) { int c = counts[base + k]; offsets[base + k] = run; run += c; }
        float rs = esum[t];                       // sum of chunks above t
        for (int k = chunk - 1; k >= 0; --k) { rs += bucketE[base + k]; suffixE[base + k] = rs; }
    }
    grid.sync();

    // ---- P3: counting-sort scatter ----
    if (g < n) {
        int pos = offsets[bg] + rg;
        sortedT[pos] = Tg;
        sortedE[pos] = Eg;
    }
    grid.sync();

    // ---- P4: risk + term + block reduce + global atomic ----
    float term = 0.f;
    if (g < n) {
        float risk = suffixE[bg + 1];
        const int p0 = offsets[bg], p1 = offsets[bg + 1];
        for (int p = p0; p < p1; ++p)
            risk += (sortedT[p] >= Tg) ? sortedE[p] : 0.f;
        term = (thg - logf(risk)) * evg;
    }
    __shared__ float red[BLOCK];
    red[threadIdx.x] = term;
    __syncthreads();
    for (int s = BLOCK / 2; s > 0; s >>= 1) {
        if (threadIdx.x < s) red[threadIdx.x] += red[threadIdx.x + s];
        __syncthreads();
    }
    if (threadIdx.x == 0) atomicAdd(acc, red[0]);
    grid.sync();

    // ---- P5: final write ----
    if (g == 0) out[0] = -acc[0] / (float)n;
}

// ---------- brute-force fallback (only if ws too small / odd n) ----------
__global__ void surv_partial_bf(const float* __restrict__ theta,
                                const float* __restrict__ T,
                                const float* __restrict__ events,
                                float* __restrict__ bsum, int n) {
    __shared__ float red[BLOCK];
    const int tid = threadIdx.x;
    const int i = blockIdx.x * BLOCK + tid;
    float term = 0.f;
    if (i < n) {
        const float Ti = T[i];
        float risk = 0.f;
        for (int j = 0; j < n; ++j)
            risk += (T[j] >= Ti) ? expf(theta[j]) : 0.f;
        term = (theta[i] - logf(risk)) * events[i];
    }
    red[tid] = term;
    __syncthreads();
    for (int s = BLOCK / 2; s > 0; s >>= 1) {
        if (tid < s) red[tid] += red[tid + s];
        __syncthreads();
    }
    if (tid == 0) bsum[blockIdx.x] = red[0];
}

__global__ void surv_final_bf(const float* __restrict__ bsum,
                              float* __restrict__ out, int nblocks, int n) {
    float v = 0.f;
    for (int b = threadIdx.x; b < nblocks; b += 64) v += bsum[b];
    for (int off = 32; off > 0; off >>= 1) v += __shfl_down(v, off, 64);
    if (threadIdx.x == 0) out[0] = -v / (float)n;
}

extern "C" void kernel_launch(void* const* d_in, const int* in_sizes, int n_in,
                              void* d_out, int out_size, void* d_ws, size_t ws_size,
                              hipStream_t stream) {
    const float* theta  = (const float*)d_in[0];
    const float* T      = (const float*)d_in[1];
    const float* events = (const float*)d_in[2];
    float* out = (float*)d_out;
    const int n = in_sizes[0];   // 16384

    const size_t need = ((size_t)KB_          // counts
                       + (KB_ + 1)            // offsets
                       + KB_                  // bucketE
                       + (KB_ + 1)            // suffixE
                       + 2 * (size_t)n        // sortedT, sortedE
                       + 1) * sizeof(float);  // acc

    if ((n % BLOCK) != 0 || ws_size < need) {
        // fallback: brute force
        const int nb = (n + BLOCK - 1) / BLOCK;
        float* bsum = (float*)d_ws;
        surv_partial_bf<<<nb, BLOCK, 0, stream>>>(theta, T, events, bsum, n);
        surv_final_bf<<<1, 64, 0, stream>>>(bsum, out, nb, n);
        return;
    }

    int*   counts  = (int*)d_ws;
    int*   offsets = counts + KB_;
    float* bucketE = (float*)(offsets + KB_ + 1);
    float* suffixE = bucketE + KB_;
    float* sortedT = suffixE + KB_ + 1;
    float* sortedE = sortedT + n;
    float* acc     = sortedE + n;

    int nblk = n / BLOCK;   // 64 blocks -> trivially co-resident on 256 CUs
    void* args[] = { (void*)&theta, (void*)&T, (void*)&events, (void*)&out,
                     (void*)&counts, (void*)&offsets, (void*)&bucketE,
                     (void*)&suffixE, (void*)&sortedT, (void*)&sortedE,
                     (void*)&acc, (void*)&n };
    hipLaunchCooperativeKernel((const void*)surv_fused,
                               dim3(nblk), dim3(BLOCK), args, 0, stream);
}

// Round 4
// 81.216 us; speedup vs baseline: 1.7345x; 1.7345x over previous
//
#include <hip/hip_runtime.h>
#include <math.h>

#define BLOCK 256
#define KB_ 16384     // value buckets (monotone bucketing => exact algorithm)
#define SCAN_T 1024

// K1: E=exp(theta), bucket id, rank via atomic hist, bucket E-sums.
__global__ void surv_hist(const float* __restrict__ theta,
                          const float* __restrict__ T,
                          int* __restrict__ counts, float* __restrict__ bucketE,
                          float* __restrict__ Earr, int* __restrict__ elemB,
                          int* __restrict__ elemR, int n) {
    int i = blockIdx.x * BLOCK + threadIdx.x;
    if (i >= n) return;
    float Tg = T[i];
    float E  = expf(theta[i]);
    int b = (int)((Tg + 6.0f) * (KB_ / 12.0f));   // monotone in Tg -> order-exact
    b = min(max(b, 0), KB_ - 1);
    int r = atomicAdd(&counts[b], 1);
    atomicAdd(&bucketE[b], E);
    Earr[i] = E; elemB[i] = b; elemR[i] = r;
}

// K2: one block: exclusive-prefix counts -> offsets; inclusive-suffix bucketE -> suffixE.
__global__ void surv_scan(const int* __restrict__ counts,
                          const float* __restrict__ bucketE,
                          int* __restrict__ offsets, float* __restrict__ suffixE,
                          int n) {
    __shared__ int   ci[SCAN_T];
    __shared__ float ce[SCAN_T];
    const int t = threadIdx.x;
    const int chunk = KB_ / SCAN_T;               // 16
    const int base = t * chunk;
    int cs = 0; float es = 0.f;
    for (int k = 0; k < chunk; ++k) { cs += counts[base + k]; es += bucketE[base + k]; }
    ci[t] = cs; ce[t] = es;
    __syncthreads();
    for (int s = 1; s < SCAN_T; s <<= 1) {        // Hillis-Steele: prefix(ci), suffix(ce)
        int   a = (t >= s)          ? ci[t - s] : 0;
        float f = (t + s < SCAN_T)  ? ce[t + s] : 0.f;
        __syncthreads();
        ci[t] += a; ce[t] += f;
        __syncthreads();
    }
    int run = ci[t] - cs;                         // exclusive prefix of chunk sums
    for (int k = 0; k < chunk; ++k) { offsets[base + k] = run; run += counts[base + k]; }
    float rs = ce[t] - es;                        // exclusive suffix of chunk sums
    for (int k = chunk - 1; k >= 0; --k) { rs += bucketE[base + k]; suffixE[base + k] = rs; }
    if (t == 0) { offsets[KB_] = n; suffixE[KB_] = 0.f; }
}

// K3: counting-sort scatter.
__global__ void surv_scatter(const float* __restrict__ T, const float* __restrict__ Earr,
                             const int* __restrict__ elemB, const int* __restrict__ elemR,
                             const int* __restrict__ offsets,
                             float* __restrict__ sortedT, float* __restrict__ sortedE, int n) {
    int i = blockIdx.x * BLOCK + threadIdx.x;
    if (i >= n) return;
    int b = elemB[i];
    int pos = offsets[b] + elemR[i];
    sortedT[pos] = T[i];
    sortedE[pos] = Earr[i];
}

// K4: risk = suffixE[b+1] + exact in-bucket scan; term; block reduce.
__global__ void surv_risk(const float* __restrict__ theta, const float* __restrict__ T,
                          const float* __restrict__ events,
                          const int* __restrict__ elemB, const int* __restrict__ offsets,
                          const float* __restrict__ suffixE,
                          const float* __restrict__ sortedT, const float* __restrict__ sortedE,
                          float* __restrict__ bsum, int n) {
    __shared__ float red[BLOCK];
    const int tid = threadIdx.x;
    const int i = blockIdx.x * BLOCK + tid;
    float term = 0.f;
    if (i < n) {
        int b = elemB[i];
        float Ti = T[i];
        float risk = suffixE[b + 1];
        const int p0 = offsets[b], p1 = offsets[b + 1];
        for (int p = p0; p < p1; ++p)
            risk += (sortedT[p] >= Ti) ? sortedE[p] : 0.f;
        term = (theta[i] - logf(risk)) * events[i];
    }
    red[tid] = term;
    __syncthreads();
    for (int s = BLOCK / 2; s > 0; s >>= 1) {
        if (tid < s) red[tid] += red[tid + s];
        __syncthreads();
    }
    if (tid == 0) bsum[blockIdx.x] = red[0];
}

// K5: final reduce -> -mean.
__global__ void surv_final(const float* __restrict__ bsum, float* __restrict__ out,
                           int nblocks, int n) {
    float v = 0.f;
    for (int b = threadIdx.x; b < nblocks; b += 64) v += bsum[b];
    for (int off = 32; off > 0; off >>= 1) v += __shfl_down(v, off, 64);
    if (threadIdx.x == 0) out[0] = -v / (float)n;
}

// ---------- brute-force fallback ----------
__global__ void surv_partial_bf(const float* __restrict__ theta, const float* __restrict__ T,
                                const float* __restrict__ events, float* __restrict__ bsum, int n) {
    __shared__ float red[BLOCK];
    const int tid = threadIdx.x;
    const int i = blockIdx.x * BLOCK + tid;
    float term = 0.f;
    if (i < n) {
        const float Ti = T[i];
        float risk = 0.f;
        for (int j = 0; j < n; ++j)
            risk += (T[j] >= Ti) ? expf(theta[j]) : 0.f;
        term = (theta[i] - logf(risk)) * events[i];
    }
    red[tid] = term;
    __syncthreads();
    for (int s = BLOCK / 2; s > 0; s >>= 1) {
        if (tid < s) red[tid] += red[tid + s];
        __syncthreads();
    }
    if (tid == 0) bsum[blockIdx.x] = red[0];
}

extern "C" void kernel_launch(void* const* d_in, const int* in_sizes, int n_in,
                              void* d_out, int out_size, void* d_ws, size_t ws_size,
                              hipStream_t stream) {
    const float* theta  = (const float*)d_in[0];
    const float* T      = (const float*)d_in[1];
    const float* events = (const float*)d_in[2];
    float* out = (float*)d_out;
    const int n = in_sizes[0];                  // 16384
    const int nbi = (n + BLOCK - 1) / BLOCK;    // 64

    // ws layout (4B units): counts[KB_], bucketE[KB_]  <-- contiguous zero region
    //                       offsets[KB_+1], suffixE[KB_+1],
    //                       sortedT[n], sortedE[n], Earr[n], elemB[n], elemR[n], bsum[nbi]
    const size_t need = ((size_t)2 * KB_ + 2 * (KB_ + 1) + 5 * (size_t)n + nbi) * 4;

    if ((size_t)ws_size < need) {
        float* bsum = (float*)d_ws;
        surv_partial_bf<<<nbi, BLOCK, 0, stream>>>(theta, T, events, bsum, n);
        surv_final<<<1, 64, 0, stream>>>(bsum, out, nbi, n);
        return;
    }

    int*   counts  = (int*)d_ws;
    float* bucketE = (float*)(counts + KB_);
    int*   offsets = (int*)(bucketE + KB_);
    float* suffixE = (float*)(offsets + KB_ + 1);
    float* sortedT = suffixE + KB_ + 1;
    float* sortedE = sortedT + n;
    float* Earr    = sortedE + n;
    int*   elemB   = (int*)(Earr + n);
    int*   elemR   = elemB + n;
    float* bsum    = (float*)(elemR + n);

    hipMemsetAsync(d_ws, 0, (size_t)2 * KB_ * 4, stream);   // zero counts+bucketE
    surv_hist<<<nbi, BLOCK, 0, stream>>>(theta, T, counts, bucketE, Earr, elemB, elemR, n);
    surv_scan<<<1, SCAN_T, 0, stream>>>(counts, bucketE, offsets, suffixE, n);
    surv_scatter<<<nbi, BLOCK, 0, stream>>>(T, Earr, elemB, elemR, offsets, sortedT, sortedE, n);
    surv_risk<<<nbi, BLOCK, 0, stream>>>(theta, T, events, elemB, offsets, suffixE,
                                         sortedT, sortedE, bsum, n);
    surv_final<<<1, 64, 0, stream>>>(bsum, out, nbi, n);
}